// Round 9
// baseline (805.558 us; speedup 1.0000x reference)
//
#include <hip/hip_runtime.h>
#include <hip/hip_bf16.h>

#define DEV_INLINE __device__ __forceinline__

constexpr int kN   = 50000;
constexpr int kNT  = 300000;
constexpr int kR   = 64;
constexpr int kRP  = 16;
constexpr int kE   = 32;
constexpr int kC   = 32;
constexpr int kLW  = 64;
constexpr int kNRP = kN * kRP;     // 800000
constexpr int kChunks = (kN + 255) / 256;   // 196

typedef __attribute__((ext_vector_type(8))) short s8v;    // 8 bf16 (4 VGPRs)
typedef __attribute__((ext_vector_type(4))) float f32x4;  // MFMA acc

DEV_INLINE short f2bf(float f) {   // fp32 -> bf16 bits, RNE
  union { float f; unsigned u; } v; v.f = f;
  unsigned r = (v.u + 0x7fffu + ((v.u >> 16) & 1u)) >> 16;
  return (short)r;
}
DEV_INLINE float bf2f(short s) {
  union { unsigned u; float f; } v; v.u = ((unsigned)(unsigned short)s) << 16;
  return v.f;
}
DEV_INLINE float bflo(unsigned u) { union { unsigned x; float f; } a; a.x = u << 16;        return a.f; }
DEV_INLINE float bfhi(unsigned u) { union { unsigned x; float f; } a; a.x = u & 0xffff0000u; return a.f; }

union U4S8 { uint4 u; s8v s; };

// split 8 fp32 -> hi (truncated bf16) + lo (exact residual, truncated bf16)
DEV_INLINE void split8(const float4 A, const float4 B, s8v& hi, s8v& lo) {
  const float f[8] = {A.x, A.y, A.z, A.w, B.x, B.y, B.z, B.w};
  unsigned u[8], l[8];
#pragma unroll
  for (int i = 0; i < 8; i++) { union { float f; unsigned u; } c; c.f = f[i]; u[i] = c.u; }
#pragma unroll
  for (int i = 0; i < 8; i++) {
    union { unsigned u; float f; } t; t.u = u[i] & 0xffff0000u;
    union { float f; unsigned u; } c; c.f = f[i] - t.f; l[i] = c.u;
  }
  U4S8 H, L;
  H.u.x = (u[1] & 0xffff0000u) | (u[0] >> 16);
  H.u.y = (u[3] & 0xffff0000u) | (u[2] >> 16);
  H.u.z = (u[5] & 0xffff0000u) | (u[4] >> 16);
  H.u.w = (u[7] & 0xffff0000u) | (u[6] >> 16);
  L.u.x = (l[1] & 0xffff0000u) | (l[0] >> 16);
  L.u.y = (l[3] & 0xffff0000u) | (l[2] >> 16);
  L.u.z = (l[5] & 0xffff0000u) | (l[4] >> 16);
  L.u.w = (l[7] & 0xffff0000u) | (l[6] >> 16);
  hi = H.s; lo = L.s;
}

// ---------- K0: degree counts for both CSRs ----------
__global__ void __launch_bounds__(256)
k_count(const int* __restrict__ s_idx, const int* __restrict__ o_idx,
        int* __restrict__ cnt_s, int* __restrict__ cnt_o) {
  const int e = blockIdx.x * 256 + threadIdx.x;
  if (e < kNT) {
    atomicAdd(&cnt_s[s_idx[e]], 1);
    atomicAdd(&cnt_o[o_idx[e]], 1);
  }
}

// ---------- parallel scan, phase 1 ----------
__global__ void __launch_bounds__(256)
k_scan_p1(const int* __restrict__ cnt_s, const int* __restrict__ cnt_o,
          int* __restrict__ rp_s, int* __restrict__ rp_o,
          int* __restrict__ bs_s, int* __restrict__ bs_o) {
  const int b = blockIdx.x;
  const bool iso = b >= kChunks;
  const int chunk = iso ? b - kChunks : b;
  const int* cnt = iso ? cnt_o : cnt_s;
  int* rp = iso ? rp_o : rp_s;
  int* bs = iso ? bs_o : bs_s;
  __shared__ int ws[4];
  const int tid = threadIdx.x, wave = tid >> 6, lane = tid & 63;
  const int i = chunk * 256 + tid;
  int v = (i < kN) ? cnt[i] : 0;
  int incl = v;
#pragma unroll
  for (int off = 1; off < 64; off <<= 1) {
    int tmp = __shfl_up(incl, off, 64);
    if (lane >= off) incl += tmp;
  }
  if (lane == 63) ws[wave] = incl;
  __syncthreads();
  int add = 0;
#pragma unroll
  for (int w = 0; w < 4; w++) if (w < wave) add += ws[w];
  incl += add;
  if (i < kN) rp[i + 1] = incl;
  if (tid == 255) bs[chunk] = incl;
}

// ---------- phase 2 ----------
__global__ void __launch_bounds__(256)
k_scan_p2(int* __restrict__ bs_s, int* __restrict__ bs_o) {
  __shared__ int ws[4];
  const int tid = threadIdx.x, wave = tid >> 6, lane = tid & 63;
#pragma unroll 1
  for (int a = 0; a < 2; a++) {
    int* bs = a ? bs_o : bs_s;
    const int v = (tid < kChunks) ? bs[tid] : 0;
    int incl = v;
#pragma unroll
    for (int off = 1; off < 64; off <<= 1) {
      int tmp = __shfl_up(incl, off, 64);
      if (lane >= off) incl += tmp;
    }
    if (lane == 63) ws[wave] = incl;
    __syncthreads();
    int add = 0;
#pragma unroll
    for (int w = 0; w < 4; w++) if (w < wave) add += ws[w];
    incl += add;
    __syncthreads();
    if (tid < kChunks) bs[tid] = incl - v;
    __syncthreads();
  }
}

// ---------- phase 3 ----------
__global__ void __launch_bounds__(256)
k_scan_p3(const int* __restrict__ bs_s, const int* __restrict__ bs_o,
          int* __restrict__ rp_s, int* __restrict__ rp_o) {
  const int b = blockIdx.x;
  const bool iso = b >= kChunks;
  const int chunk = iso ? b - kChunks : b;
  int* rp = iso ? rp_o : rp_s;
  const int* bs = iso ? bs_o : bs_s;
  const int i = chunk * 256 + threadIdx.x;
  if (i < kN) rp[i + 1] += bs[chunk];
  if (chunk == 0 && threadIdx.x == 0) rp[0] = 0;
}

// ---------- scatter edge ids into both CSRs ----------
__global__ void __launch_bounds__(256)
k_scatter2(const int* __restrict__ s_idx, const int* __restrict__ o_idx,
           const int* __restrict__ rowptr_s, int* __restrict__ cursor_s,
           const int* __restrict__ rowptr_o, int* __restrict__ cursor_o,
           int2* __restrict__ eo_s, int* __restrict__ e_o) {
  const int e = blockIdx.x * 256 + threadIdx.x;
  if (e < kNT) {
    const int s = s_idx[e], o = o_idx[e];
    const int ps = atomicAdd(&cursor_s[s], 1);
    int2 v; v.x = e; v.y = o;
    eo_s[rowptr_s[s] + ps] = v;
    const int po = atomicAdd(&cursor_o[o], 1);
    e_o[rowptr_o[o] + po] = e;
  }
}

// ---------- W-frag prep: split-bf16 fragments in B-layout, once ----------
// Wf shorts: BaH[8192] | BaL[8192] | BbH[2048] | BbL[2048] | W2H[16384] | W2L[16384]
__global__ void __launch_bounds__(256)
k_wprep(const float* __restrict__ W1a, const float* __restrict__ W1b,
        const float* __restrict__ W2a, const float* __restrict__ W2b,
        const float* __restrict__ W2, short* __restrict__ Wf) {
  const int tid = threadIdx.x;
  if (blockIdx.x == 0) {
    for (int i = tid; i < 8192; i += 256) {
      const int j = i & 7, lane = (i >> 3) & 63, ks = (i >> 9) & 1,
                nt = (i >> 10) & 3, mlp = i >> 12;
      const int p = lane & 15, q8 = (lane >> 4) * 8;
      const float* Wa = mlp ? W2a : W1a;
      const float v = Wa[(ks * 32 + q8 + j) * kLW + nt * 16 + p];
      union { float f; unsigned u; } c; c.f = v;
      const short h = (short)(c.u >> 16);
      Wf[i] = h;
      Wf[8192 + i] = f2bf(v - bf2f(h));
    }
    for (int i = tid; i < 2048; i += 256) {
      const int j = i & 7, lane = (i >> 3) & 63, ks = (i >> 9) & 1, mlp = i >> 10;
      const int p = lane & 15, q8 = (lane >> 4) * 8;
      const float* Wb = mlp ? W2b : W1b;
      const float v = Wb[(ks * 32 + q8 + j) * kRP + p];
      union { float f; unsigned u; } c; c.f = v;
      const short h = (short)(c.u >> 16);
      Wf[16384 + i] = h;
      Wf[18432 + i] = f2bf(v - bf2f(h));
    }
  } else {
    for (int i = tid; i < 16384; i += 256) {
      const int j = i & 7, ln = (i >> 3) & 63, nt = (i >> 9) & 1, ks = i >> 10;
      const int pp = ln & 15, qq8 = (ln >> 4) * 8;
      const float v = W2[(ks * 32 + qq8 + j) * 32 + nt * 16 + pp];
      const short h = f2bf(v);
      Wf[20480 + i] = h;
      Wf[36864 + i] = f2bf(v - bf2f(h));
    }
  }
}

// ---------- K1: BOTH edge MLPs + softmax via split-bf16 MFMA ----------
// Layouts [m89/m91/m118]: A[m=lane&15][k=(lane>>4)*8+j],
// B[k=(lane>>4)*8+j][n=lane&15], C/D col=lane&15, row=(lane>>4)*4+reg.
__global__ void __launch_bounds__(256)
k_lat(const float* __restrict__ nhots, const short* __restrict__ Wf,
      const float* __restrict__ b1a, const float* __restrict__ b1b,
      const float* __restrict__ b2a, const float* __restrict__ b2b,
      float* __restrict__ lat1o, float* __restrict__ lat2o) {
  __shared__ float sHf[4][16][68];       // 17.4 KB
  const int tid = threadIdx.x;
  const int wave = tid >> 6, lane = tid & 63;
  const int p = lane & 15, q = lane >> 4, q8 = (lane >> 4) * 8;

  const uint4* BaH4 = (const uint4*)(Wf);
  const uint4* BaL4 = (const uint4*)(Wf + 8192);
  const uint4* BbH4 = (const uint4*)(Wf + 16384);
  const uint4* BbL4 = (const uint4*)(Wf + 18432);

  const int w2 = (blockIdx.x * 4 + wave) * 2;   // first of 2 tile slots

#pragma unroll 1
  for (int mlp = 0; mlp < 2; mlp++) {
    s8v Bh[4][2], Bl[4][2], Bbh[2], Bbl[2];
#pragma unroll
    for (int nt = 0; nt < 4; nt++)
#pragma unroll
      for (int ks = 0; ks < 2; ks++) {
        U4S8 a, b;
        a.u = BaH4[((mlp * 4 + nt) * 2 + ks) * 64 + lane];
        b.u = BaL4[((mlp * 4 + nt) * 2 + ks) * 64 + lane];
        Bh[nt][ks] = a.s; Bl[nt][ks] = b.s;
      }
#pragma unroll
    for (int ks = 0; ks < 2; ks++) {
      U4S8 a, b;
      a.u = BbH4[(mlp * 2 + ks) * 64 + lane];
      b.u = BbL4[(mlp * 2 + ks) * 64 + lane];
      Bbh[ks] = a.s; Bbl[ks] = b.s;
    }
    const float* bA = mlp ? b2a : b1a;
    const float* bB = mlp ? b2b : b1b;
    float bav[4];
#pragma unroll
    for (int nt = 0; nt < 4; nt++) bav[nt] = bA[nt * 16 + p];
    const float bbv = bB[p];
    float* lato = mlp ? lat2o : lat1o;

#pragma unroll 1
    for (int t = 0; t < 2; t++) {
      const int slot = w2 + t;
      if (slot >= kNT / 32) break;
      const int eb = slot * 32;
#pragma unroll 1
      for (int ht = 0; ht < 2; ht++) {
        const int mb = eb + ht * 16;
        const float* arow = nhots + (size_t)(mb + p) * kR;
        s8v ah[2], al[2];
#pragma unroll
        for (int ks = 0; ks < 2; ks++) {
          const float4 xa = *(const float4*)(arow + ks * 32 + q8);
          const float4 xb = *(const float4*)(arow + ks * 32 + q8 + 4);
          split8(xa, xb, ah[ks], al[ks]);
        }
        f32x4 acc[4];
#pragma unroll
        for (int nt = 0; nt < 4; nt++) {
          acc[nt] = (f32x4)0.f;
#pragma unroll
          for (int ks = 0; ks < 2; ks++) {
            acc[nt] = __builtin_amdgcn_mfma_f32_16x16x32_bf16(ah[ks], Bh[nt][ks], acc[nt], 0, 0, 0);
            acc[nt] = __builtin_amdgcn_mfma_f32_16x16x32_bf16(ah[ks], Bl[nt][ks], acc[nt], 0, 0, 0);
            acc[nt] = __builtin_amdgcn_mfma_f32_16x16x32_bf16(al[ks], Bh[nt][ks], acc[nt], 0, 0, 0);
          }
        }
#pragma unroll
        for (int nt = 0; nt < 4; nt++)
#pragma unroll
          for (int reg = 0; reg < 4; reg++)
            sHf[wave][q * 4 + reg][nt * 16 + p] = fmaxf(acc[nt][reg] + bav[nt], 0.f);
        const float* hr = &sHf[wave][p][0];
        s8v hh[2], hl[2];
#pragma unroll
        for (int ks = 0; ks < 2; ks++) {
          const float4 xa = *(const float4*)(hr + ks * 32 + q8);
          const float4 xb = *(const float4*)(hr + ks * 32 + q8 + 4);
          split8(xa, xb, hh[ks], hl[ks]);
        }
        f32x4 accB = (f32x4)0.f;
#pragma unroll
        for (int ks = 0; ks < 2; ks++) {
          accB = __builtin_amdgcn_mfma_f32_16x16x32_bf16(hh[ks], Bbh[ks], accB, 0, 0, 0);
          accB = __builtin_amdgcn_mfma_f32_16x16x32_bf16(hh[ks], Bbl[ks], accB, 0, 0, 0);
          accB = __builtin_amdgcn_mfma_f32_16x16x32_bf16(hl[ks], Bbh[ks], accB, 0, 0, 0);
        }
#pragma unroll
        for (int reg = 0; reg < 4; reg++) {
          const float v = accB[reg] + bbv;
          float m = v;
#pragma unroll
          for (int d = 1; d < 16; d <<= 1) m = fmaxf(m, __shfl_xor(m, d));
          const float e = __expf(v - m);
          float sum = e;
#pragma unroll
          for (int d = 1; d < 16; d <<= 1) sum += __shfl_xor(sum, d);
          lato[(size_t)(mb + q * 4 + reg) * kRP + p] = e / sum;
        }
      }
    }
  }
}

// ---------- per-node partial sums C1[o][k], R2[s][k] ----------
__global__ void __launch_bounds__(256)
k_partials(const int* __restrict__ rowptr_s, const int2* __restrict__ eo_s,
           const int* __restrict__ rowptr_o, const int* __restrict__ e_o,
           const float* __restrict__ lat1, const float* __restrict__ lat2,
           float* __restrict__ C1, float* __restrict__ R2,
           float* __restrict__ tots) {
  __shared__ float st[2][4];
  const int tid = threadIdx.x;
  const int wave = tid >> 6, lane = tid & 63;
  const int k = lane & 15, g = lane >> 4;
  float t1 = 0.f, t2 = 0.f;
  const int nw = gridDim.x * 4;
  for (int n = blockIdx.x * 4 + wave; n < kN; n += nw) {
    {
      const int beg = rowptr_s[n], end = rowptr_s[n + 1];
      float acc = 0.f;
      for (int j = beg + g; j < end; j += 4)
        acc += lat2[(size_t)eo_s[j].x * kRP + k];
      acc += __shfl_xor(acc, 16); acc += __shfl_xor(acc, 32);
      if (g == 0) { R2[n * kRP + k] = acc; if (k == 0) t2 += acc; }
    }
    {
      const int beg = rowptr_o[n], end = rowptr_o[n + 1];
      float acc = 0.f;
      for (int j = beg + g; j < end; j += 4)
        acc += lat1[(size_t)e_o[j] * kRP + k];
      acc += __shfl_xor(acc, 16); acc += __shfl_xor(acc, 32);
      if (g == 0) { C1[n * kRP + k] = acc; if (k == 0) t1 += acc; }
    }
  }
  if (lane == 0) { st[0][wave] = t1; st[1][wave] = t2; }
  __syncthreads();
  if (tid == 0) {
    atomicAdd(&tots[0], st[0][0] + st[0][1] + st[0][2] + st[0][3]);
    atomicAdd(&tots[1], st[1][0] + st[1][1] + st[1][2] + st[1][3]);
  }
}

// ---------- csinv/rsinv via divisor enumeration ----------
__global__ void __launch_bounds__(256)
k_norms(const float* __restrict__ C1, const float* __restrict__ R2,
        const float* __restrict__ tots,
        float* __restrict__ csinv, float* __restrict__ rsinv) {
  const int m = blockIdx.x * 256 + threadIdx.x;
  if (m < kNRP) {
    float cs = (m == 0) ? tots[0] : 0.f;
    float rs = (m == 0) ? tots[1] : 0.f;
#pragma unroll
    for (int k = 1; k < kRP; k++) {
      if (m % k == 0) {
        const int q = m / k;
        if (q < kN) { cs += C1[q * kRP + k]; rs += R2[q * kRP + k]; }
      }
    }
    csinv[m] = (cs != 0.f) ? 1.f / cs : 0.f;
    rsinv[m] = (rs != 0.f) ? 1.f / rs : 0.f;
  }
}

// ---------- G build: G8[o][lane][j] bf16 = csinv[o*k]*wt1[o*k][c] ----------
__global__ void __launch_bounds__(256)
k_gbuild(const float* __restrict__ wt1, const float* __restrict__ csinv,
         unsigned* __restrict__ G8u) {
  __shared__ float sT[16][33];
  const int o = blockIdx.x;
  const int tid = threadIdx.x;
#pragma unroll
  for (int half = 0; half < 2; half++) {
    const int e = half * 256 + tid;
    const int k = e >> 5, c = e & 31;
    const int idx = o * k;
    sT[k][c] = csinv[idx] * wt1[(size_t)idx * kE + c];
  }
  __syncthreads();
  const int l = tid >> 2;
  const int c = l >> 1, kh = l & 1;
  const int j0 = (2 * tid) & 7;
  const int k0 = kh * 8 + j0, k1 = k0 + 1;
  const unsigned lo = (unsigned short)f2bf(sT[k0][c]);
  const unsigned hi = (unsigned short)f2bf(sT[k1][c]);
  G8u[(size_t)o * 256 + tid] = lo | (hi << 16);
}

// ---------- layer-1 gather via G: 16 B/lane/edge ----------
__global__ void __launch_bounds__(256)
k_layer1g(const int* __restrict__ rowptr, const int2* __restrict__ eo,
          const float* __restrict__ lat1, const uint4* __restrict__ G8,
          const float* __restrict__ bias1, float* __restrict__ h) {
  const int tid = threadIdx.x;
  const int wave = tid >> 6, lane = tid & 63;
  const int c = lane >> 1, kh = lane & 1;
  const float b1 = bias1[c];
  for (int s = blockIdx.x * 4 + wave; s < kN; s += gridDim.x * 4) {
    float acc = 0.f;
    const int beg = rowptr[s], end = rowptr[s + 1];
    for (int j = beg; j < end; j++) {
      const int2 E = eo[j];
      const uint4 g = G8[(size_t)E.y * 64 + lane];
      const float4 la = *(const float4*)(lat1 + (size_t)E.x * kRP + kh * 8);
      const float4 lb = *(const float4*)(lat1 + (size_t)E.x * kRP + kh * 8 + 4);
      acc = fmaf(la.x, bflo(g.x), acc); acc = fmaf(la.y, bfhi(g.x), acc);
      acc = fmaf(la.z, bflo(g.y), acc); acc = fmaf(la.w, bfhi(g.y), acc);
      acc = fmaf(lb.x, bflo(g.z), acc); acc = fmaf(lb.y, bfhi(g.z), acc);
      acc = fmaf(lb.z, bflo(g.w), acc); acc = fmaf(lb.w, bfhi(g.w), acc);
    }
    acc += __shfl_xor(acc, 1);
    if (kh == 0) h[(size_t)s * kE + c] = fmaxf(acc + b1, 0.f);
  }
}

// ---------- per-s walk -> Ub[s][k-1][c] bf16; also hrow0 partials (k=0) ----------
__global__ void __launch_bounds__(256)
k_u(const int* __restrict__ rowptr, const int2* __restrict__ eo,
    const float* __restrict__ lat2, const float* __restrict__ rsinv,
    const float* __restrict__ h, short* __restrict__ Ub,
    float* __restrict__ pblk) {
  __shared__ float sacc[kE];
  const int tid = threadIdx.x;
  const int wave = tid >> 6, lane = tid & 63;
  const int c = lane & 31, half = lane >> 5;
  if (tid < kE) sacc[tid] = 0.f;
  __syncthreads();
  float hpart = 0.f;
  for (int s = blockIdx.x * 4 + wave; s < kN; s += gridDim.x * 4) {
    float u[8];
#pragma unroll
    for (int kk = 0; kk < 8; kk++) u[kk] = 0.f;
    const int beg = rowptr[s], end = rowptr[s + 1];
    for (int j = beg; j < end; j++) {
      const int2 E = eo[j];
      const float hv = h[(size_t)E.y * kE + c];
      const float4* lp = (const float4*)(lat2 + (size_t)E.x * kRP) + half * 2;
      const float4 la = lp[0], lb = lp[1];
      const float lv[8] = {la.x, la.y, la.z, la.w, lb.x, lb.y, lb.z, lb.w};
#pragma unroll
      for (int kk = 0; kk < 8; kk++) u[kk] = fmaf(lv[kk], hv, u[kk]);
    }
    if (half == 0) hpart += u[0];
#pragma unroll
    for (int kk = 0; kk < 8; kk++) {
      const int k = half * 8 + kk;
      if (k >= 1)
        Ub[((size_t)s * 15 + (k - 1)) * kE + c] = f2bf(u[kk] * rsinv[s * k]);
    }
  }
  atomicAdd(&sacc[c], hpart);
  __syncthreads();
  if (tid < kE) pblk[(size_t)blockIdx.x * kE + tid] = sacc[tid];
}

// ---------- reduce per-block hrow0 partials ----------
__global__ void __launch_bounds__(256)
k_hred(const float* __restrict__ pblk, int nblk, float* __restrict__ hrow0) {
  __shared__ float sacc[kE];
  const int tid = threadIdx.x;
  if (tid < kE) sacc[tid] = 0.f;
  __syncthreads();
  const int total = nblk * kE;
  float r = 0.f;
  for (int i = blockIdx.x * 256 + tid; i < total; i += gridDim.x * 256)
    r += pblk[i];
  atomicAdd(&sacc[tid & 31], r);
  __syncthreads();
  if (tid < kE) atomicAdd(&hrow0[tid], sacc[tid]);
}

// ---------- fused: H2 divisor-gather (in-register) + einsum MFMA ----------
// A-frag step ks: a[j] = H2[mb+p][r=ks][c=q8+j] = sum of Ub hits (+hrow0 for m=0).
__global__ void __launch_bounds__(256)
k_einsum_fused(const short* __restrict__ Ub, const float* __restrict__ hrow0,
               const float* __restrict__ rsinv, const short* __restrict__ Wf,
               const float* __restrict__ bias2, float* __restrict__ out) {
  __shared__ short sBWh[16384];    // 32 KB
  __shared__ short sBWl[16384];    // 32 KB
  const int tid = threadIdx.x;
  {
    const uint4* src_h = (const uint4*)(Wf + 20480);
    const uint4* src_l = (const uint4*)(Wf + 36864);
    uint4* dh = (uint4*)sBWh;
    uint4* dl = (uint4*)sBWl;
    for (int i = tid; i < 2048; i += 256) { dh[i] = src_h[i]; dl[i] = src_l[i]; }
  }
  __syncthreads();
  const int wave = tid >> 6, lane = tid & 63;
  const int p = lane & 15, q = lane >> 4, q8 = q * 8;
  const float bias0 = bias2[p], bias1v = bias2[16 + p];
  const float rs0 = rsinv[0];
  for (int tile = blockIdx.x * 4 + wave; tile < kN / 16; tile += gridDim.x * 4) {
    const int mb = tile * 16;
    const int n = mb + p;
    int nm[kRP];
#pragma unroll
    for (int k = 2; k < kRP; k++) nm[k] = n % k;   // magic-mul, const k
    f32x4 acc0 = (f32x4)0.f, acc1 = (f32x4)0.f;
#pragma unroll
    for (int ks = 0; ks < 16; ks++) {
      float row[8];
#pragma unroll
      for (int i = 0; i < 8; i++) row[i] = 0.f;
      if (ks == 0) {
        // k=1 always hits: s = n
        const uint4 g = *(const uint4*)(Ub + (size_t)n * 15 * kE + q8);
        row[0] += bflo(g.x); row[1] += bfhi(g.x);
        row[2] += bflo(g.y); row[3] += bfhi(g.y);
        row[4] += bflo(g.z); row[5] += bfhi(g.z);
        row[6] += bflo(g.w); row[7] += bfhi(g.w);
        if (n == 0) {
#pragma unroll
          for (int i = 0; i < 8; i++) row[i] += hrow0[q8 + i] * rs0;
        }
      }
#pragma unroll
      for (int k = (ks == 0 ? 2 : ks + 1); k < kRP; k++) {
        const int target = (k - (ks * 50000) % k) % k;   // compile-time const
        if (nm[k] == target) {
          const int s = (ks * 50000 + n) / k;            // magic-div, const k
          const uint4 g = *(const uint4*)(Ub + ((size_t)s * 15 + (k - 1)) * kE + q8);
          row[0] += bflo(g.x); row[1] += bfhi(g.x);
          row[2] += bflo(g.y); row[3] += bfhi(g.y);
          row[4] += bflo(g.z); row[5] += bfhi(g.z);
          row[6] += bflo(g.w); row[7] += bfhi(g.w);
        }
      }
      s8v a;
#pragma unroll
      for (int i = 0; i < 8; i++) a[i] = f2bf(row[i]);
      const s8v b0h = *(const s8v*)(sBWh + ((ks * 2 + 0) * 64 + lane) * 8);
      const s8v b0l = *(const s8v*)(sBWl + ((ks * 2 + 0) * 64 + lane) * 8);
      const s8v b1h = *(const s8v*)(sBWh + ((ks * 2 + 1) * 64 + lane) * 8);
      const s8v b1l = *(const s8v*)(sBWl + ((ks * 2 + 1) * 64 + lane) * 8);
      acc0 = __builtin_amdgcn_mfma_f32_16x16x32_bf16(a, b0h, acc0, 0, 0, 0);
      acc0 = __builtin_amdgcn_mfma_f32_16x16x32_bf16(a, b0l, acc0, 0, 0, 0);
      acc1 = __builtin_amdgcn_mfma_f32_16x16x32_bf16(a, b1h, acc1, 0, 0, 0);
      acc1 = __builtin_amdgcn_mfma_f32_16x16x32_bf16(a, b1l, acc1, 0, 0, 0);
    }
#pragma unroll
    for (int reg = 0; reg < 4; reg++) {
      const int nn = mb + q * 4 + reg;
      out[(size_t)nn * kC + p]      = acc0[reg] + bias0;
      out[(size_t)nn * kC + 16 + p] = acc1[reg] + bias1v;
    }
  }
}

// ---------- host ----------
extern "C" void kernel_launch(void* const* d_in, const int* in_sizes, int n_in,
                              void* d_out, int out_size, void* d_ws, size_t ws_size,
                              hipStream_t stream) {
  (void)in_sizes; (void)n_in; (void)out_size; (void)ws_size;
  const int* s_idx = (const int*)d_in[0];
  const int* o_idx = (const int*)d_in[1];
  const float* nhots = (const float*)d_in[2];
  const float* W1a = (const float*)d_in[3]; const float* b1a = (const float*)d_in[4];
  const float* W1b = (const float*)d_in[5]; const float* b1b = (const float*)d_in[6];
  const float* W2a = (const float*)d_in[7]; const float* b2a = (const float*)d_in[8];
  const float* W2b = (const float*)d_in[9]; const float* b2b = (const float*)d_in[10];
  const float* wt1 = (const float*)d_in[11]; const float* wt2 = (const float*)d_in[12];
  const float* bias1 = (const float*)d_in[13]; const float* bias2 = (const float*)d_in[14];

  char* ws = (char*)d_ws;
  size_t off = 0;
  auto alloc = [&](size_t bytes) -> char* {
    char* p = ws + off;
    off = (off + bytes + 255) & ~(size_t)255;
    return p;
  };
  char*  z0       = ws;                                    // zero region start
  int*   cnt_s    = (int*)  alloc((size_t)kN * 4);
  int*   cnt_o    = (int*)  alloc((size_t)kN * 4);
  int*   cursor_s = (int*)  alloc((size_t)kN * 4);
  int*   cursor_o = (int*)  alloc((size_t)kN * 4);
  float* tots     = (float*)alloc(8);
  float* hrow0    = (float*)alloc((size_t)kE * 4);
  const size_t zbytes = (size_t)((ws + off) - z0);         // ~0.8 MB
  short* Wf       = (short*)alloc((size_t)53248 * 2);      // 104 KB W frags
  int*   bs_s     = (int*)  alloc((size_t)kChunks * 4);
  int*   bs_o     = (int*)  alloc((size_t)kChunks * 4);
  int*   rowptr_s = (int*)  alloc((size_t)(kN + 1) * 4);
  int*   rowptr_o = (int*)  alloc((size_t)(kN + 1) * 4);
  float* pblk     = (float*)alloc((size_t)12500 * kE * 4); // 1.6 MB
  float* lat2     = (float*)alloc((size_t)kNT * kRP * 4);  // 19.2 MB
  int2*  eo_s     = (int2*) alloc((size_t)kNT * 8);        // 2.4 MB
  int*   e_o      = (int*)  alloc((size_t)kNT * 4);        // 1.2 MB
  float* C1       = (float*)alloc((size_t)kNRP * 4);       // 3.2 MB
  float* R2       = (float*)alloc((size_t)kNRP * 4);       // 3.2 MB
  float* csinv    = (float*)alloc((size_t)kNRP * 4);       // 3.2 MB
  float* rsinv    = (float*)alloc((size_t)kNRP * 4);       // 3.2 MB
  float* hbuf     = (float*)alloc((size_t)kN * kE * 4);    // 6.4 MB
  short* Ub       = (short*)alloc((size_t)kN * 15 * kE * 2);   // 48 MB
  char*  Greg     = alloc((size_t)kN * 1024);                  // 51.2 MB (G8)
  float* lat1     = (float*)Ub;        // alias: lat1 dead before k_u writes Ub
  unsigned* G8u   = (unsigned*)Greg;
  // total ~144 MB (< 150.6 MB proven by round 3)

  hipMemsetAsync(z0, 0, zbytes, stream);

  const dim3 blk(256);
  const int gEdges = (kNT + 255) / 256;
  const int gLat = ((kNT / 32 + 1) / 2 + 3) / 4;   // 2 tiles/wave, 4 waves/block

  k_count<<<gEdges, blk, 0, stream>>>(s_idx, o_idx, cnt_s, cnt_o);
  k_scan_p1<<<2 * kChunks, blk, 0, stream>>>(cnt_s, cnt_o, rowptr_s, rowptr_o, bs_s, bs_o);
  k_scan_p2<<<1, blk, 0, stream>>>(bs_s, bs_o);
  k_scan_p3<<<2 * kChunks, blk, 0, stream>>>(bs_s, bs_o, rowptr_s, rowptr_o);
  k_scatter2<<<gEdges, blk, 0, stream>>>(s_idx, o_idx, rowptr_s, cursor_s,
                                         rowptr_o, cursor_o, eo_s, e_o);
  k_wprep<<<2, blk, 0, stream>>>(W1a, W1b, W2a, W2b, wt2, Wf);
  k_lat<<<gLat, blk, 0, stream>>>(nhots, Wf, b1a, b1b, b2a, b2b, lat1, lat2);
  k_partials<<<6250, blk, 0, stream>>>(rowptr_s, eo_s, rowptr_o, e_o,
                                       lat1, lat2, C1, R2, tots);
  k_norms<<<(kNRP + 255) / 256, blk, 0, stream>>>(C1, R2, tots, csinv, rsinv);
  k_gbuild<<<kN, blk, 0, stream>>>(wt1, csinv, G8u);
  k_layer1g<<<12500, blk, 0, stream>>>(rowptr_s, eo_s, lat1, (const uint4*)G8u, bias1, hbuf);
  k_u<<<12500, blk, 0, stream>>>(rowptr_s, eo_s, lat2, rsinv, hbuf, Ub, pblk);
  k_hred<<<50, blk, 0, stream>>>(pblk, 12500, hrow0);
  k_einsum_fused<<<782, blk, 0, stream>>>(Ub, hrow0, rsinv, Wf, bias2, (float*)d_out);
}